// Round 2
// baseline (2192.821 us; speedup 1.0000x reference)
//
#include <hip/hip_runtime.h>
#include <math.h>

#define BB 2
#define NN 4096
#define DIM 128
#define DIN 256
#define DST 16
#define DTR 8
#define NROW (BB*NN)          // 8192
#define SOUT (BB*NN*DIM)      // 1048576
#define EPSF 1e-5f

__device__ __forceinline__ float siluf(float x){ return x / (1.f + __expf(-x)); }
__device__ __forceinline__ float softplusf(float x){ return fmaxf(x,0.f) + log1pf(__expf(-fabsf(x))); }

// ---------------- K1: residual add + LN + channel swap ----------------
// grid: NROW blocks, 64 threads. Each thread owns channels d and d+64.
__global__ void k_ln_swap(const float* __restrict__ I1, const float* __restrict__ I2,
                          const float* __restrict__ I1r, const float* __restrict__ I2r,
                          const float* __restrict__ w1, const float* __restrict__ b1,
                          const float* __restrict__ w2, const float* __restrict__ b2,
                          float* __restrict__ out, float* __restrict__ xs1, float* __restrict__ xs2){
  const int row = blockIdx.x;
  const int tid = threadIdx.x;
  const int d0 = tid, d1 = tid + 64;
  const int base = row * DIM;
  float r1a = I1[base+d0] + I1r[base+d0];
  float r1b = I1[base+d1] + I1r[base+d1];
  float r2a = I2[base+d0] + I2r[base+d0];
  float r2b = I2[base+d1] + I2r[base+d1];
  out[2*SOUT+base+d0]=r1a; out[2*SOUT+base+d1]=r1b;
  out[3*SOUT+base+d0]=r2a; out[3*SOUT+base+d1]=r2b;
  float s1=r1a+r1b, q1=fmaf(r1a,r1a,r1b*r1b);
  float s2=r2a+r2b, q2=fmaf(r2a,r2a,r2b*r2b);
  #pragma unroll
  for (int m=32;m;m>>=1){
    s1+=__shfl_xor(s1,m,64); q1+=__shfl_xor(q1,m,64);
    s2+=__shfl_xor(s2,m,64); q2+=__shfl_xor(q2,m,64);
  }
  const float inv = 1.f/128.f;
  float mu1=s1*inv, mu2=s2*inv;
  float var1=q1*inv-mu1*mu1, var2=q2*inv-mu2*mu2;
  float is1=rsqrtf(var1+EPSF), is2=rsqrtf(var2+EPSF);
  float n1a=(r1a-mu1)*is1*w1[d0]+b1[d0];
  float n1b=(r1b-mu1)*is1*w1[d1]+b1[d1];
  float n2a=(r2a-mu2)*is2*w2[d0]+b2[d0];
  float n2b=(r2b-mu2)*is2*w2[d1]+b2[d1];
  // even channel takes the OTHER stream's normalized value (d1 has same parity as d0)
  bool e0 = (d0 & 1) == 0;
  xs1[base+d0] = e0 ? n2a : n1a;  xs1[base+d1] = e0 ? n2b : n1b;
  xs2[base+d0] = e0 ? n1a : n2a;  xs2[base+d1] = e0 ? n1b : n2b;
}

// ---------------- K2: xz = x @ W_in  (128 -> 512) ----------------
// grid: (NROW, 2 streams), 256 threads; thread computes cols 2t, 2t+1.
__global__ void k_inproj(const float* __restrict__ xs1, const float* __restrict__ xs2,
                         const float* __restrict__ Win1, const float* __restrict__ Win2,
                         float* __restrict__ xz){
  const int row = blockIdx.x;
  const int s = blockIdx.y;
  const int tid = threadIdx.x;
  const float* x = s ? xs2 : xs1;
  const float2* W2 = (const float2*)(s ? Win2 : Win1);
  float* o = xz + (size_t)s*(size_t)NROW*512 + (size_t)row*512;
  __shared__ float xrow[DIM];
  if (tid < DIM) xrow[tid] = x[row*DIM+tid];
  __syncthreads();
  float a0=0.f, a1=0.f;
  #pragma unroll 8
  for (int k=0;k<DIM;k++){
    float2 w = W2[k*256+tid];
    float xv = xrow[k];
    a0 = fmaf(xv, w.x, a0);
    a1 = fmaf(xv, w.y, a1);
  }
  o[2*tid] = a0; o[2*tid+1] = a1;
}

// ---------------- K3: depthwise conv4 + silu, x_dbl = xc@W_x, dt ----------------
// grid: (NROW, 2), 64 threads.
__global__ void k_conv_proj(const float* __restrict__ xz,
                            const float* __restrict__ cw1, const float* __restrict__ cb1,
                            const float* __restrict__ Wx1, const float* __restrict__ Wdt1,
                            const float* __restrict__ dtb1,
                            const float* __restrict__ cw2, const float* __restrict__ cb2,
                            const float* __restrict__ Wx2, const float* __restrict__ Wdt2,
                            const float* __restrict__ dtb2,
                            float* __restrict__ xc, float* __restrict__ xd, float* __restrict__ dtg){
  const int row = blockIdx.x;           // b*N + t
  const int s = blockIdx.y;
  const int tid = threadIdx.x;          // 0..63
  const int b = row >> 12, t = row & (NN-1);
  const float* xzq = xz + (size_t)s*NROW*512;
  float* xcq = xc + (size_t)s*NROW*256;
  float* xdq = xd + (size_t)s*NROW*40;
  float* dtq = dtg + (size_t)s*NROW*256;
  const float* cw = s?cw2:cw1; const float* cb = s?cb2:cb1;
  const float* Wx = s?Wx2:Wx1; const float* Wdt = s?Wdt2:Wdt1; const float* dtb = s?dtb2:dtb1;
  __shared__ float xcs[DIN];
  __shared__ float xds[40];
  #pragma unroll
  for (int j=0;j<4;j++){
    int d = tid + 64*j;
    float acc = cb[d];
    #pragma unroll
    for (int k=0;k<4;k++){
      int tt = t - 3 + k;
      if (tt >= 0) acc = fmaf(xzq[(size_t)(b*NN+tt)*512 + d], cw[d*4+k], acc);
    }
    float v = siluf(acc);
    xcs[d] = v;
    xcq[(size_t)row*256 + d] = v;
  }
  __syncthreads();
  if (tid < 40){
    float acc = 0.f;
    #pragma unroll 8
    for (int k=0;k<DIN;k++) acc = fmaf(xcs[k], Wx[k*40+tid], acc);
    xds[tid] = acc;
    xdq[(size_t)row*40 + tid] = acc;
  }
  __syncthreads();
  #pragma unroll
  for (int j=0;j<4;j++){
    int d = tid + 64*j;
    float acc = dtb[d];
    #pragma unroll
    for (int r=0;r<DTR;r++) acc = fmaf(xds[r], Wdt[r*256+d], acc);
    dtq[(size_t)row*256 + d] = softplusf(acc);
  }
}

// ---------------- K4: selective scan ----------------
// grid: (64 d-groups, B, 2 streams), 64 threads = 4 d * 16 states.
// y written into the xp half of xz (xp dead after K3).
__global__ void k_scan(const float* __restrict__ dtg, const float* __restrict__ xc,
                       const float* __restrict__ xd,
                       const float* __restrict__ Alog1, const float* __restrict__ Alog2,
                       float* __restrict__ xz){
  const int tid = threadIdx.x;
  const int si = tid & 15, di = tid >> 4;
  const int d = blockIdx.x*4 + di;
  const int b = blockIdx.y;
  const int s = blockIdx.z;
  const float* dtq = dtg + (size_t)s*NROW*256 + (size_t)b*NN*256;
  const float* xcq = xc  + (size_t)s*NROW*256 + (size_t)b*NN*256;
  const float* xdq = xd  + (size_t)s*NROW*40  + (size_t)b*NN*40;
  float* yq = xz + (size_t)s*NROW*512 + (size_t)b*NN*512;
  const float* Alog = s?Alog2:Alog1;
  const float Aval = -__expf(Alog[d*16+si]);
  float h = 0.f;
  #pragma unroll 4
  for (int t=0;t<NN;t++){
    float dtv = dtq[(size_t)t*256 + d];
    float xcv = xcq[(size_t)t*256 + d];
    float bm  = xdq[t*40 + 8 + si];
    float cm  = xdq[t*40 + 24 + si];
    float da = __expf(dtv * Aval);
    h = fmaf(da, h, dtv*bm*xcv);
    float c = h * cm;
    c += __shfl_xor(c, 1, 16);
    c += __shfl_xor(c, 2, 16);
    c += __shfl_xor(c, 4, 16);
    c += __shfl_xor(c, 8, 16);
    if (si == 0) yq[(size_t)t*512 + d] = c;
  }
}

// ---------------- K5: v = (y + xc*D)*silu(z); out = v @ W_out ----------------
// grid: (NROW, 2), 128 threads; thread computes one output column.
__global__ void k_out(const float* __restrict__ xz, const float* __restrict__ xc,
                      const float* __restrict__ D1, const float* __restrict__ D2,
                      const float* __restrict__ Wo1, const float* __restrict__ Wo2,
                      float* __restrict__ out){
  const int row = blockIdx.x;
  const int s = blockIdx.y;
  const int tid = threadIdx.x;
  const float* xzq = xz + (size_t)s*NROW*512 + (size_t)row*512;
  const float* xcq = xc + (size_t)s*NROW*256 + (size_t)row*256;
  const float* Dw = s?D2:D1; const float* Wo = s?Wo2:Wo1;
  __shared__ float v[DIN];
  #pragma unroll
  for (int j=0;j<2;j++){
    int d = tid + 128*j;
    float yv = xzq[d];
    float zv = xzq[256+d];
    v[d] = fmaf(xcq[d], Dw[d], yv) * siluf(zv);
  }
  __syncthreads();
  float acc = 0.f;
  #pragma unroll 8
  for (int k=0;k<DIN;k++) acc = fmaf(v[k], Wo[k*128+tid], acc);
  out[(size_t)s*SOUT + (size_t)row*128 + tid] = acc;
}

extern "C" void kernel_launch(void* const* d_in, const int* in_sizes, int n_in,
                              void* d_out, int out_size, void* d_ws, size_t ws_size,
                              hipStream_t stream) {
  const float* I1   = (const float*)d_in[0];
  const float* I2   = (const float*)d_in[1];
  const float* I1r  = (const float*)d_in[2];
  const float* I2r  = (const float*)d_in[3];
  const float* ln1w = (const float*)d_in[4];
  const float* ln1b = (const float*)d_in[5];
  const float* ln2w = (const float*)d_in[6];
  const float* ln2b = (const float*)d_in[7];
  const float* Win1 = (const float*)d_in[8];
  const float* cw1  = (const float*)d_in[9];
  const float* cb1  = (const float*)d_in[10];
  const float* Wx1  = (const float*)d_in[11];
  const float* Wdt1 = (const float*)d_in[12];
  const float* dtb1 = (const float*)d_in[13];
  const float* Al1  = (const float*)d_in[14];
  const float* D1   = (const float*)d_in[15];
  const float* Wo1  = (const float*)d_in[16];
  const float* Win2 = (const float*)d_in[17];
  const float* cw2  = (const float*)d_in[18];
  const float* cb2  = (const float*)d_in[19];
  const float* Wx2  = (const float*)d_in[20];
  const float* Wdt2 = (const float*)d_in[21];
  const float* dtb2 = (const float*)d_in[22];
  const float* Al2  = (const float*)d_in[23];
  const float* D2   = (const float*)d_in[24];
  const float* Wo2  = (const float*)d_in[25];
  float* out = (float*)d_out;

  float* ws  = (float*)d_ws;
  float* xs1 = ws;                                  // 1,048,576
  float* xs2 = xs1 + (size_t)SOUT;                  // 1,048,576
  float* xz  = xs2 + (size_t)SOUT;                  // 2 * 8192*512 = 8,388,608
  float* xc  = xz  + (size_t)2*NROW*512;            // 2 * 8192*256 = 4,194,304
  float* xd  = xc  + (size_t)2*NROW*256;            // 2 * 8192*40  =   655,360
  float* dtg = xd  + (size_t)2*NROW*40;             // 2 * 8192*256 = 4,194,304
  // total ~78.1 MB of float workspace

  k_ln_swap<<<dim3(NROW), dim3(64), 0, stream>>>(I1, I2, I1r, I2r, ln1w, ln1b, ln2w, ln2b,
                                                 out, xs1, xs2);
  k_inproj<<<dim3(NROW,2), dim3(256), 0, stream>>>(xs1, xs2, Win1, Win2, xz);
  k_conv_proj<<<dim3(NROW,2), dim3(64), 0, stream>>>(xz, cw1, cb1, Wx1, Wdt1, dtb1,
                                                     cw2, cb2, Wx2, Wdt2, dtb2,
                                                     xc, xd, dtg);
  k_scan<<<dim3(64,BB,2), dim3(64), 0, stream>>>(dtg, xc, xd, Al1, Al2, xz);
  k_out<<<dim3(NROW,2), dim3(128), 0, stream>>>(xz, xc, D1, D2, Wo1, Wo2, out);
}

// Round 3
// 348.365 us; speedup vs baseline: 6.2946x; 6.2946x over previous
//
#include <hip/hip_runtime.h>
#include <math.h>

#define BB 2
#define NN 4096
#define DIM 128
#define DIN 256
#define DST 16
#define DTR 8
#define NROW (BB*NN)          // 8192
#define SOUT (BB*NN*DIM)      // 1048576
#define NC 64                 // chunks per sequence
#define CL 64                 // chunk length (NC*CL == NN)
#define EPSF 1e-5f

__device__ __forceinline__ float siluf(float x){ return x / (1.f + __expf(-x)); }
__device__ __forceinline__ float softplusf(float x){ return fmaxf(x,0.f) + log1pf(__expf(-fabsf(x))); }

// ---------------- K1: residual add + LN + channel swap ----------------
__global__ void k_ln_swap(const float* __restrict__ I1, const float* __restrict__ I2,
                          const float* __restrict__ I1r, const float* __restrict__ I2r,
                          const float* __restrict__ w1, const float* __restrict__ b1,
                          const float* __restrict__ w2, const float* __restrict__ b2,
                          float* __restrict__ out, float* __restrict__ xs1, float* __restrict__ xs2){
  const int row = blockIdx.x;
  const int tid = threadIdx.x;
  const int d0 = tid, d1 = tid + 64;
  const int base = row * DIM;
  float r1a = I1[base+d0] + I1r[base+d0];
  float r1b = I1[base+d1] + I1r[base+d1];
  float r2a = I2[base+d0] + I2r[base+d0];
  float r2b = I2[base+d1] + I2r[base+d1];
  out[2*SOUT+base+d0]=r1a; out[2*SOUT+base+d1]=r1b;
  out[3*SOUT+base+d0]=r2a; out[3*SOUT+base+d1]=r2b;
  float s1=r1a+r1b, q1=fmaf(r1a,r1a,r1b*r1b);
  float s2=r2a+r2b, q2=fmaf(r2a,r2a,r2b*r2b);
  #pragma unroll
  for (int m=32;m;m>>=1){
    s1+=__shfl_xor(s1,m,64); q1+=__shfl_xor(q1,m,64);
    s2+=__shfl_xor(s2,m,64); q2+=__shfl_xor(q2,m,64);
  }
  const float inv = 1.f/128.f;
  float mu1=s1*inv, mu2=s2*inv;
  float var1=q1*inv-mu1*mu1, var2=q2*inv-mu2*mu2;
  float is1=rsqrtf(var1+EPSF), is2=rsqrtf(var2+EPSF);
  float n1a=(r1a-mu1)*is1*w1[d0]+b1[d0];
  float n1b=(r1b-mu1)*is1*w1[d1]+b1[d1];
  float n2a=(r2a-mu2)*is2*w2[d0]+b2[d0];
  float n2b=(r2b-mu2)*is2*w2[d1]+b2[d1];
  bool e0 = (d0 & 1) == 0;
  xs1[base+d0] = e0 ? n2a : n1a;  xs1[base+d1] = e0 ? n2b : n1b;
  xs2[base+d0] = e0 ? n1a : n2a;  xs2[base+d1] = e0 ? n1b : n2b;
}

// ---------------- K2: xz = x @ W_in (128 -> 512), 8 rows/block ----------------
// grid: (NROW/8, 2), 256 threads. Weight read once per 8 rows.
__global__ void k_inproj(const float* __restrict__ xs1, const float* __restrict__ xs2,
                         const float* __restrict__ Win1, const float* __restrict__ Win2,
                         float* __restrict__ xz){
  const int rb = blockIdx.x;            // row block, 8 rows
  const int s = blockIdx.y;
  const int tid = threadIdx.x;          // 0..255 -> cols 2t,2t+1
  const float* x = s ? xs2 : xs1;
  const float2* W2 = (const float2*)(s ? Win2 : Win1);
  __shared__ __align__(16) float xrow[8*DIM];
  ((float4*)xrow)[tid] = ((const float4*)(x + (size_t)rb*8*DIM))[tid];
  __syncthreads();
  float ax[8], ay[8];
  #pragma unroll
  for (int r=0;r<8;r++){ ax[r]=0.f; ay[r]=0.f; }
  #pragma unroll 4
  for (int k4=0;k4<DIM/4;k4++){
    float2 w0 = W2[(4*k4+0)*256+tid];
    float2 w1 = W2[(4*k4+1)*256+tid];
    float2 w2 = W2[(4*k4+2)*256+tid];
    float2 w3 = W2[(4*k4+3)*256+tid];
    #pragma unroll
    for (int r=0;r<8;r++){
      float4 xv = *(const float4*)&xrow[r*DIM + 4*k4];
      ax[r] = fmaf(xv.x, w0.x, ax[r]); ay[r] = fmaf(xv.x, w0.y, ay[r]);
      ax[r] = fmaf(xv.y, w1.x, ax[r]); ay[r] = fmaf(xv.y, w1.y, ay[r]);
      ax[r] = fmaf(xv.z, w2.x, ax[r]); ay[r] = fmaf(xv.z, w2.y, ay[r]);
      ax[r] = fmaf(xv.w, w3.x, ax[r]); ay[r] = fmaf(xv.w, w3.y, ay[r]);
    }
  }
  #pragma unroll
  for (int r=0;r<8;r++){
    float2* o = (float2*)(xz + (size_t)s*NROW*512 + (size_t)(rb*8+r)*512);
    o[tid] = make_float2(ax[r], ay[r]);
  }
}

// ---------------- K3: depthwise conv4 + silu, x_dbl = xc@W_x, dt ----------------
__global__ void k_conv_proj(const float* __restrict__ xz,
                            const float* __restrict__ cw1, const float* __restrict__ cb1,
                            const float* __restrict__ Wx1, const float* __restrict__ Wdt1,
                            const float* __restrict__ dtb1,
                            const float* __restrict__ cw2, const float* __restrict__ cb2,
                            const float* __restrict__ Wx2, const float* __restrict__ Wdt2,
                            const float* __restrict__ dtb2,
                            float* __restrict__ xc, float* __restrict__ xd, float* __restrict__ dtg){
  const int row = blockIdx.x;
  const int s = blockIdx.y;
  const int tid = threadIdx.x;
  const int b = row >> 12, t = row & (NN-1);
  const float* xzq = xz + (size_t)s*NROW*512;
  float* xcq = xc + (size_t)s*NROW*256;
  float* xdq = xd + (size_t)s*NROW*40;
  float* dtq = dtg + (size_t)s*NROW*256;
  const float* cw = s?cw2:cw1; const float* cb = s?cb2:cb1;
  const float* Wx = s?Wx2:Wx1; const float* Wdt = s?Wdt2:Wdt1; const float* dtb = s?dtb2:dtb1;
  __shared__ float xcs[DIN];
  __shared__ float xds[40];
  #pragma unroll
  for (int j=0;j<4;j++){
    int d = tid + 64*j;
    float acc = cb[d];
    #pragma unroll
    for (int k=0;k<4;k++){
      int tt = t - 3 + k;
      if (tt >= 0) acc = fmaf(xzq[(size_t)(b*NN+tt)*512 + d], cw[d*4+k], acc);
    }
    float v = siluf(acc);
    xcs[d] = v;
    xcq[(size_t)row*256 + d] = v;
  }
  __syncthreads();
  if (tid < 40){
    float acc = 0.f;
    #pragma unroll 8
    for (int k=0;k<DIN;k++) acc = fmaf(xcs[k], Wx[k*40+tid], acc);
    xds[tid] = acc;
    xdq[(size_t)row*40 + tid] = acc;
  }
  __syncthreads();
  #pragma unroll
  for (int j=0;j<4;j++){
    int d = tid + 64*j;
    float acc = dtb[d];
    #pragma unroll
    for (int r=0;r<DTR;r++) acc = fmaf(xds[r], Wdt[r*256+d], acc);
    dtq[(size_t)row*256 + d] = softplusf(acc);
  }
}

// ---------------- K4a: local chunk scan ----------------
// grid: (NC, 16 dtiles, 4 sb), 256 threads = 16 d x 16 si. tid = di*16+si.
__global__ void k_scan_local(const float* __restrict__ dtg, const float* __restrict__ xc,
                             const float* __restrict__ xd,
                             const float* __restrict__ Alog1, const float* __restrict__ Alog2,
                             float* __restrict__ Aprod, float* __restrict__ Sfin){
  const int c = blockIdx.x, dtile = blockIdx.y, sb = blockIdx.z;
  const int s = sb >> 1, b = sb & 1;
  const int tid = threadIdx.x;
  const int si = tid & 15, di = tid >> 4;
  const int d = dtile*16 + di;
  const float* dtq = dtg + (size_t)s*NROW*256 + (size_t)b*NN*256;
  const float* xcq = xc  + (size_t)s*NROW*256 + (size_t)b*NN*256;
  const float* xdq = xd  + (size_t)s*NROW*40  + (size_t)b*NN*40;
  const float* Alog = s?Alog2:Alog1;
  const float Aval = -__expf(Alog[d*16+si]);
  float h = 0.f, sdt = 0.f;
  const int t0 = c*CL;
  #pragma unroll 4
  for (int tt=0;tt<CL;tt++){
    int t = t0 + tt;
    float dtv = dtq[t*256 + d];
    float xcv = xcq[t*256 + d];
    float bm  = xdq[t*40 + 8 + si];
    float da = __expf(dtv * Aval);
    sdt += dtv;
    h = fmaf(da, h, dtv*bm*xcv);
  }
  const size_t idx = (size_t)(sb*NC + c)*4096 + dtile*256 + tid;
  Aprod[idx] = __expf(Aval*sdt);   // product of per-step decays
  Sfin[idx]  = h;
}

// ---------------- K4b: inter-chunk carry ----------------
// grid: 64 blocks, 256 threads; thread owns one (s,b,d,si) recurrence.
__global__ void k_scan_carry(const float* __restrict__ Aprod, const float* __restrict__ Sfin,
                             float* __restrict__ Hinit){
  const int bid = blockIdx.x;
  const int sb = bid >> 4;
  const int seg = (bid & 15)*256 + threadIdx.x;
  float h = 0.f;
  #pragma unroll 4
  for (int c=0;c<NC;c++){
    const size_t idx = (size_t)(sb*NC + c)*4096 + seg;
    float A = Aprod[idx];
    float S = Sfin[idx];
    Hinit[idx] = h;
    h = fmaf(A, h, S);
  }
}

// ---------------- K4c: final chunk scan + y ----------------
// y written into the xp half of xz (dead after conv).
__global__ void k_scan_final(const float* __restrict__ dtg, const float* __restrict__ xc,
                             const float* __restrict__ xd,
                             const float* __restrict__ Alog1, const float* __restrict__ Alog2,
                             const float* __restrict__ Hinit, float* __restrict__ xz){
  const int c = blockIdx.x, dtile = blockIdx.y, sb = blockIdx.z;
  const int s = sb >> 1, b = sb & 1;
  const int tid = threadIdx.x;
  const int si = tid & 15, di = tid >> 4;
  const int d = dtile*16 + di;
  const float* dtq = dtg + (size_t)s*NROW*256 + (size_t)b*NN*256;
  const float* xcq = xc  + (size_t)s*NROW*256 + (size_t)b*NN*256;
  const float* xdq = xd  + (size_t)s*NROW*40  + (size_t)b*NN*40;
  float* yq = xz + (size_t)s*NROW*512 + (size_t)b*NN*512;
  const float* Alog = s?Alog2:Alog1;
  const float Aval = -__expf(Alog[d*16+si]);
  float h = Hinit[(size_t)(sb*NC + c)*4096 + dtile*256 + tid];
  const int t0 = c*CL;
  #pragma unroll 4
  for (int tt=0;tt<CL;tt++){
    int t = t0 + tt;
    float dtv = dtq[t*256 + d];
    float xcv = xcq[t*256 + d];
    float bm  = xdq[t*40 + 8 + si];
    float cm  = xdq[t*40 + 24 + si];
    float da = __expf(dtv * Aval);
    h = fmaf(da, h, dtv*bm*xcv);
    float y = h * cm;
    y += __shfl_xor(y, 1, 16);
    y += __shfl_xor(y, 2, 16);
    y += __shfl_xor(y, 4, 16);
    y += __shfl_xor(y, 8, 16);
    if (si == 0) yq[(size_t)t*512 + d] = y;
  }
}

// ---------------- K5: v = (y + xc*D)*silu(z); out = v @ W_out, 8 rows/block ----
// grid: (NROW/8, 2), 256 threads: col = tid&127, row-half = tid>>7.
__global__ void k_out(const float* __restrict__ xz, const float* __restrict__ xc,
                      const float* __restrict__ D1, const float* __restrict__ D2,
                      const float* __restrict__ Wo1, const float* __restrict__ Wo2,
                      float* __restrict__ out){
  const int rb = blockIdx.x;
  const int s = blockIdx.y;
  const int tid = threadIdx.x;
  const int col = tid & 127, rh = tid >> 7;
  const float* xzb = xz + (size_t)s*NROW*512 + (size_t)rb*8*512;
  const float* xcb = xc + (size_t)s*NROW*256 + (size_t)rb*8*256;
  const float* Dw = s?D2:D1; const float* Wo = s?Wo2:Wo1;
  __shared__ __align__(16) float v[8*DIN];
  #pragma unroll
  for (int i=0;i<8;i++){
    int idx = tid + i*256;
    int r = idx >> 8, d = idx & 255;
    float yv = xzb[(size_t)r*512 + d];
    float zv = xzb[(size_t)r*512 + 256 + d];
    v[idx] = fmaf(xcb[r*256 + d], Dw[d], yv) * siluf(zv);
  }
  __syncthreads();
  float acc[4] = {0.f,0.f,0.f,0.f};
  #pragma unroll 4
  for (int k4=0;k4<DIN/4;k4++){
    float w0 = Wo[(4*k4+0)*128+col];
    float w1 = Wo[(4*k4+1)*128+col];
    float w2 = Wo[(4*k4+2)*128+col];
    float w3 = Wo[(4*k4+3)*128+col];
    #pragma unroll
    for (int j=0;j<4;j++){
      float4 vv = *(const float4*)&v[(rh*4+j)*DIN + 4*k4];
      acc[j] = fmaf(vv.x, w0, acc[j]);
      acc[j] = fmaf(vv.y, w1, acc[j]);
      acc[j] = fmaf(vv.z, w2, acc[j]);
      acc[j] = fmaf(vv.w, w3, acc[j]);
    }
  }
  #pragma unroll
  for (int j=0;j<4;j++)
    out[(size_t)s*SOUT + (size_t)(rb*8 + rh*4 + j)*128 + col] = acc[j];
}

extern "C" void kernel_launch(void* const* d_in, const int* in_sizes, int n_in,
                              void* d_out, int out_size, void* d_ws, size_t ws_size,
                              hipStream_t stream) {
  const float* I1   = (const float*)d_in[0];
  const float* I2   = (const float*)d_in[1];
  const float* I1r  = (const float*)d_in[2];
  const float* I2r  = (const float*)d_in[3];
  const float* ln1w = (const float*)d_in[4];
  const float* ln1b = (const float*)d_in[5];
  const float* ln2w = (const float*)d_in[6];
  const float* ln2b = (const float*)d_in[7];
  const float* Win1 = (const float*)d_in[8];
  const float* cw1  = (const float*)d_in[9];
  const float* cb1  = (const float*)d_in[10];
  const float* Wx1  = (const float*)d_in[11];
  const float* Wdt1 = (const float*)d_in[12];
  const float* dtb1 = (const float*)d_in[13];
  const float* Al1  = (const float*)d_in[14];
  const float* D1   = (const float*)d_in[15];
  const float* Wo1  = (const float*)d_in[16];
  const float* Win2 = (const float*)d_in[17];
  const float* cw2  = (const float*)d_in[18];
  const float* cb2  = (const float*)d_in[19];
  const float* Wx2  = (const float*)d_in[20];
  const float* Wdt2 = (const float*)d_in[21];
  const float* dtb2 = (const float*)d_in[22];
  const float* Al2  = (const float*)d_in[23];
  const float* D2   = (const float*)d_in[24];
  const float* Wo2  = (const float*)d_in[25];
  float* out = (float*)d_out;

  float* ws  = (float*)d_ws;
  float* xs1 = ws;                                  // 1M floats
  float* xs2 = xs1 + (size_t)SOUT;                  // 1M floats
  float* xz  = xs2 + (size_t)SOUT;                  // 8M floats
  float* xc  = xz  + (size_t)2*NROW*512;            // 4M floats
  float* xd  = xc  + (size_t)2*NROW*256;            // 640K floats
  float* dtg = xd  + (size_t)2*NROW*40;             // 4M floats
  // chunk-scan scratch overlays: xs1/xs2 dead after k_inproj; d_out[0..1M)
  // overwritten by k_out afterwards.
  float* Aprod = xs1;                               // 1M floats
  float* Sfin  = xs2;                               // 1M floats
  float* Hinit = out;                               // 1M floats (scratch until k_out)

  k_ln_swap<<<dim3(NROW), dim3(64), 0, stream>>>(I1, I2, I1r, I2r, ln1w, ln1b, ln2w, ln2b,
                                                 out, xs1, xs2);
  k_inproj<<<dim3(NROW/8,2), dim3(256), 0, stream>>>(xs1, xs2, Win1, Win2, xz);
  k_conv_proj<<<dim3(NROW,2), dim3(64), 0, stream>>>(xz, cw1, cb1, Wx1, Wdt1, dtb1,
                                                     cw2, cb2, Wx2, Wdt2, dtb2,
                                                     xc, xd, dtg);
  k_scan_local<<<dim3(NC,16,4), dim3(256), 0, stream>>>(dtg, xc, xd, Al1, Al2, Aprod, Sfin);
  k_scan_carry<<<dim3(64), dim3(256), 0, stream>>>(Aprod, Sfin, Hinit);
  k_scan_final<<<dim3(NC,16,4), dim3(256), 0, stream>>>(dtg, xc, xd, Al1, Al2, Hinit, xz);
  k_out<<<dim3(NROW/8,2), dim3(256), 0, stream>>>(xz, xc, D1, D2, Wo1, Wo2, out);
}